// Round 6
// baseline (45.352 us; speedup 1.0000x reference)
//
#include <hip/hip_runtime.h>
#include <math.h>

// Problem constants (from reference): B=8, N=512, T=8192, D=256.
#define BB 8
#define NN 512
#define TT 8192
#define DD 256

#define THREADS 256
#define BLOCKS  2048            // 8 blocks/CU on 256 CUs

// clang ext-vector: __builtin_nontemporal_store requires a pointer to a
// vector of scalars, not HIP's struct-wrapped float4.
typedef float v4f __attribute__((ext_vector_type(4)));
typedef int   v4i __attribute__((ext_vector_type(4)));

// ---------------------------------------------------------------------------
// Kernel 1 (setup): 64 blocks = 8 batches x 8 frame-chunks, 512 threads.
// Each block redundantly scans its batch's 512 durations in LDS (cheap),
// then fills seg_id + positions for its 1024-frame chunk via binary search.
//
// fp32 boundary subtlety (verified round 2): at t == start, t - c == -dur/2
// exactly; reference adds 1e-6f. For dur/2 >= 32 the half-ULP exceeds 1e-6 so
// the sum rounds back to dur/2 -> that start frame is covered by NO segment
// (weights column all zero, out row zero, positions = t).
// ---------------------------------------------------------------------------
__global__ void setup_kernel(const int* __restrict__ dur,
                             int* __restrict__ seg_id,
                             float* __restrict__ positions) {
    __shared__ int s_end[NN + 1];   // s_end[n] = start of segment n; s_end[NN] = T
    __shared__ int s_cov[NN];       // 1 if segment's start frame is covered
    const int b     = blockIdx.x >> 3;
    const int chunk = blockIdx.x & 7;
    const int n     = threadIdx.x;

    const int d = dur[b * NN + n];
    s_end[n + 1] = d;
    if (n == 0) s_end[0] = 0;
    int acc = d;
    for (int off = 1; off < NN; off <<= 1) {
        __syncthreads();
        const int v = (n >= off) ? s_end[n + 1 - off] : 0;
        __syncthreads();
        acc += v;
        s_end[n + 1] = acc;
    }
    const float h = 0.5f * (float)d;
    s_cov[n] = (fabsf(1e-6f - h) < h) ? 1 : 0;
    __syncthreads();

    const int base = b * TT;
    const int t0   = chunk * (TT / 8);
    for (int t = t0 + n; t < t0 + TT / 8; t += NN) {
        int lo = 0, hi = NN - 1;          // find lo: s_end[lo] <= t < s_end[lo+1]
        while (lo < hi) {
            const int mid = (lo + hi) >> 1;
            if (t < s_end[mid + 1]) hi = mid; else lo = mid + 1;
        }
        const int st = s_end[lo];
        int   sg;
        float pv;
        if (t == st && !s_cov[lo]) { sg = -1; pv = (float)t; }
        else                       { sg = lo; pv = (float)(t - st); }
        seg_id[base + t]    = sg;
        positions[base + t] = pv;
    }
}

// ---------------------------------------------------------------------------
// Kernel 2 (bigwrite): 2^19 threads, fully-unrolled compile-time trip counts.
//
// Out part: t = tid>>6, d4 = (tid&63)*4; the 8 seg loads (one per batch) are
// independent and hoisted, then 8 x-row gathers + 8 nt stores -> deep MLP.
//
// Weights part: thread owns (b, n5, tq); ONE int4 seg load serves 16 stores
// (n = n5 + 32k), cutting seg L2 read traffic 16x. Lanes consecutive in tq
// -> every store is a contiguous 1 KB wave-write.
//
// All big-array stores are nontemporal: 197 MB of pure streaming output
// shouldn't allocate in L2 (keeps x + seg resident).
// ---------------------------------------------------------------------------
__global__ void __launch_bounds__(THREADS)
bigwrite_kernel(const float* __restrict__ x,
                const int* __restrict__ seg_id,
                float* __restrict__ outp,
                float* __restrict__ w) {
    const int tid = blockIdx.x * THREADS + threadIdx.x;   // 0 .. 2^19-1

    // ---- out: out[b,t,:] = x[b, seg[b,t], :] ----
    const int d4 = (tid & 63) << 2;
    const int tf = tid >> 6;                 // frame 0..8191 (one frame/wave)
    int segv[BB];
    #pragma unroll
    for (int b = 0; b < BB; ++b)
        segv[b] = seg_id[b * TT + tf];
    #pragma unroll
    for (int b = 0; b < BB; ++b) {
        v4f v = (v4f)(0.0f);
        if (segv[b] >= 0)
            v = *(const v4f*)(x + (((size_t)b * NN + segv[b]) * DD + d4));
        __builtin_nontemporal_store(v,
            (v4f*)(outp + (((size_t)b * TT + tf) * DD + d4)));
    }

    // ---- weights: w[b,n,t..t+3] = (seg[b,t..t+3] == n) ----
    const int tq = tid & 2047;               // 11 bits: t/4
    const int n5 = (tid >> 11) & 31;         // 5 bits:  n mod 32
    const int b  = tid >> 16;                // 3 bits
    const int t  = tq << 2;
    const v4i sg = *(const v4i*)(seg_id + b * TT + t);
    float* wb = w + ((size_t)b << 22) + t;   // + n*TT added per iteration
    #pragma unroll
    for (int k = 0; k < 16; ++k) {
        const int n = n5 + (k << 5);
        v4f o;
        o.x = (sg.x == n) ? 1.0f : 0.0f;
        o.y = (sg.y == n) ? 1.0f : 0.0f;
        o.z = (sg.z == n) ? 1.0f : 0.0f;
        o.w = (sg.w == n) ? 1.0f : 0.0f;
        __builtin_nontemporal_store(o, (v4f*)(wb + ((size_t)n << 13)));
    }
}

extern "C" void kernel_launch(void* const* d_in, const int* in_sizes, int n_in,
                              void* d_out, int out_size, void* d_ws, size_t ws_size,
                              hipStream_t stream) {
    const float* x  = (const float*)d_in[0];
    const int* dur  = (const int*)d_in[1];

    // Output layout: positions [B,T] | out [B,T,D] | weights [B,N,T]
    float* pos  = (float*)d_out;
    float* outp = pos + (size_t)BB * TT;
    float* w    = outp + (size_t)BB * TT * DD;

    // Workspace: seg_id [B*T] ints (256 KB)
    int* seg = (int*)d_ws;

    setup_kernel<<<BB * 8, NN, 0, stream>>>(dur, seg, pos);
    bigwrite_kernel<<<BLOCKS, THREADS, 0, stream>>>(x, seg, outp, w);
}